// Round 1
// 365.287 us; speedup vs baseline: 1.0510x; 1.0510x over previous
//
#include <hip/hip_runtime.h>
#include <cmath>

// MNEMatch: B pairs of [N,D] fp32; S = x1 @ x2^T per pair; greedy max matching
// (== sort entries desc + scan taking row/col-free entries); out[b]=tanh(sum/N).
#define NN 256
#define DD 384
#define CAPS 2048        // sorted candidate capacity (mean ~1350 at T=40, 19 sigma below CAPS)
#define THRESH 40.0f     // ~2.04 sigma of N(0,384)

typedef unsigned long long ull;
typedef short bf16x8 __attribute__((ext_vector_type(8)));
typedef float f32x4  __attribute__((ext_vector_type(4)));

// ---------------- Kernel 1: batched S = A @ B^T via bf16 MFMA --------------
// 128(rows) x 64(cols) tile, 1024 blocks (4/CU), register prefetch of next
// K-slab overlaps global latency with frag reads + MFMA.
__device__ __forceinline__ unsigned bfpack2(float lo, float hi) {
  return (__float_as_uint(hi) & 0xFFFF0000u) | (__float_as_uint(lo) >> 16);
}

__global__ __launch_bounds__(256) void gemm_bt_mfma(const float* __restrict__ X1,
                                                    const float* __restrict__ X2,
                                                    float* __restrict__ S) {
  const int pair  = blockIdx.z;
  const int rbase = blockIdx.y * 128;
  const int cbase = blockIdx.x * 64;

  __shared__ unsigned short As[128][40];  // 32 k-vals + pad
  __shared__ unsigned short Bs[64][40];

  const int tid   = threadIdx.x;
  const int lane  = tid & 63;
  const int wave  = tid >> 6;          // wave w -> rows 32w..32w+31, all 64 cols
  const int q     = lane >> 4, mi = lane & 15;

  const int srowA = tid >> 1, halfA = tid & 1;     // A: 128 rows x 32 k
  const int srowB = tid >> 2, qB    = tid & 3;     // B:  64 rows x 32 k

  const float* Abase = X1 + (size_t)pair * NN * DD + (size_t)(rbase + srowA) * DD + halfA * 16;
  const float* Bbase = X2 + (size_t)pair * NN * DD + (size_t)(cbase + srowB) * DD + qB * 8;

  f32x4 acc[2][4] = {};

  float4 pa0, pa1, pa2, pa3, pb0, pb1;
  {
    const float4* ap = (const float4*)(Abase);
    const float4* bp = (const float4*)(Bbase);
    pa0 = ap[0]; pa1 = ap[1]; pa2 = ap[2]; pa3 = ap[3];
    pb0 = bp[0]; pb1 = bp[1];
  }

  for (int k0 = 0; k0 < DD; k0 += 32) {
    __syncthreads();
    {
      uint4 w0 = make_uint4(bfpack2(pa0.x,pa0.y), bfpack2(pa0.z,pa0.w),
                            bfpack2(pa1.x,pa1.y), bfpack2(pa1.z,pa1.w));
      uint4 w1 = make_uint4(bfpack2(pa2.x,pa2.y), bfpack2(pa2.z,pa2.w),
                            bfpack2(pa3.x,pa3.y), bfpack2(pa3.z,pa3.w));
      *(uint4*)&As[srowA][halfA*16]     = w0;
      *(uint4*)&As[srowA][halfA*16 + 8] = w1;
      uint4 v0 = make_uint4(bfpack2(pb0.x,pb0.y), bfpack2(pb0.z,pb0.w),
                            bfpack2(pb1.x,pb1.y), bfpack2(pb1.z,pb1.w));
      *(uint4*)&Bs[srowB][qB*8] = v0;
    }
    __syncthreads();
    const int kn = k0 + 32;
    if (kn < DD) {                      // issue next slab's loads early
      const float4* ap = (const float4*)(Abase + kn);
      const float4* bp = (const float4*)(Bbase + kn);
      pa0 = ap[0]; pa1 = ap[1]; pa2 = ap[2]; pa3 = ap[3];
      pb0 = bp[0]; pb1 = bp[1];
    }
    bf16x8 af[2], bf[4];
#pragma unroll
    for (int i = 0; i < 2; ++i) af[i] = *(const bf16x8*)&As[wave*32 + i*16 + mi][q*8];
#pragma unroll
    for (int j = 0; j < 4; ++j) bf[j] = *(const bf16x8*)&Bs[j*16 + mi][q*8];
#pragma unroll
    for (int i = 0; i < 2; ++i)
#pragma unroll
      for (int j = 0; j < 4; ++j)
        acc[i][j] = __builtin_amdgcn_mfma_f32_16x16x32_bf16(af[i], bf[j], acc[i][j], 0, 0, 0);
  }

  float* Sp = S + (size_t)pair * NN * NN;
#pragma unroll
  for (int i = 0; i < 2; ++i)
#pragma unroll
    for (int j = 0; j < 4; ++j)
#pragma unroll
      for (int r2 = 0; r2 < 4; ++r2) {
        const int rowg = rbase + wave*32 + i*16 + q*4 + r2;  // C/D: row = quad*4+reg
        const int colg = cbase + j*16 + mi;                  //      col = lane&15
        Sp[(size_t)rowg * NN + colg] = acc[i][j][r2];
      }
}

// ---------------- DPP wave64 argmax (result in lane 63) --------------------
#define DPP_STEP(ctrl, rmask)                                                  \
  {                                                                            \
    int vi  = __float_as_int(v);                                               \
    int v2b = __builtin_amdgcn_update_dpp(vi, vi, (ctrl), (rmask), 0xf, false);\
    int i2  = __builtin_amdgcn_update_dpp(c,  c,  (ctrl), (rmask), 0xf, false);\
    float v2 = __int_as_float(v2b);                                            \
    if (v2 > v || (v2 == v && i2 < c)) { v = v2; c = i2; }                     \
  }

__device__ __forceinline__ void dpp_argmax(float& v, int& c) {
  DPP_STEP(0x111, 0xf)  // row_shr:1
  DPP_STEP(0x112, 0xf)  // row_shr:2
  DPP_STEP(0x114, 0xf)  // row_shr:4
  DPP_STEP(0x118, 0xf)  // row_shr:8
  DPP_STEP(0x142, 0xa)  // row_bcast:15
  DPP_STEP(0x143, 0xc)  // row_bcast:31
}
#undef DPP_STEP

__device__ __forceinline__ float rdlane_f(float v, int l) {
  return __int_as_float(__builtin_amdgcn_readlane(__float_as_int(v), l));
}

// masked full-row argmax over alive cols (slow exact path, k > 64 only)
__device__ __forceinline__ void rescan_row(const float* __restrict__ Sp, int r,
                                           ull a0, ull a1, ull a2, ull a3,
                                           int lane, float& rv, int& rc) {
  float v = -INFINITY; int c = -1;
#pragma unroll
  for (int j = 0; j < 4; ++j) {
    const int cc = j*64 + lane;
    float x = Sp[(size_t)r * NN + cc];
    ull aj = (j==0) ? a0 : (j==1) ? a1 : (j==2) ? a2 : a3;
    float mv = ((aj >> lane) & 1ull) ? x : -INFINITY;
    if (mv > v) { v = mv; c = cc; }
  }
  dpp_argmax(v, c);
  rv = rdlane_f(v, 63);
  rc = __builtin_amdgcn_readlane(c, 63);
}

// i-th set bit (ascending) of a 256-bit mask; 0 if fewer than i+1 bits set
__device__ __forceinline__ int nth_set4(ull m0, ull m1, ull m2, ull m3, int n) {
  int base = 0; ull m = m0;
  int c = __popcll(m);
  if (n >= c) { n -= c; m = m1; base = 64; c = __popcll(m);
    if (n >= c) { n -= c; m = m2; base = 128; c = __popcll(m);
      if (n >= c) { n -= c; m = m3; base = 192; } } }
  for (int i = 0; i < n; ++i) m &= m - 1;
  return m ? (base + (int)__builtin_ctzll(m)) : 0;
}

// max+argmax over one compacted LDS row, cols masked by colAlive.
// 4 independent max chains (unrolled) to cut the dependent-latency chain.
__device__ __forceinline__ void row_max_lds(const float* __restrict__ rowp,
                                            ull colAlive, float& rmv, int& rac) {
  float m0 = -INFINITY, m1 = -INFINITY, m2 = -INFINITY, m3 = -INFINITY;
  int   a0 = 0, a1 = 1, a2 = 2, a3 = 3;
#pragma unroll
  for (int j = 0; j < 64; j += 4) {
    const unsigned g = (unsigned)(colAlive >> j);
    float x0 = (g & 1u) ? rowp[j]     : -INFINITY;
    float x1 = (g & 2u) ? rowp[j + 1] : -INFINITY;
    float x2 = (g & 4u) ? rowp[j + 2] : -INFINITY;
    float x3 = (g & 8u) ? rowp[j + 3] : -INFINITY;
    if (x0 > m0) { m0 = x0; a0 = j; }
    if (x1 > m1) { m1 = x1; a1 = j + 1; }
    if (x2 > m2) { m2 = x2; a2 = j + 2; }
    if (x3 > m3) { m3 = x3; a3 = j + 3; }
  }
  float mv = m0; int ai = a0;
  if (m1 > mv) { mv = m1; ai = a1; }
  if (m2 > mv) { mv = m2; ai = a2; }
  if (m3 > mv) { mv = m3; ai = a3; }
  rmv = mv; rac = ai;
}

// ------------- Kernel 2: sort + ordered scan, one block per pair -----------
__global__ __launch_bounds__(256) void sort_scan_match(const float* __restrict__ S,
                                                       float* __restrict__ out) {
  const int pair = blockIdx.x;
  const float* Sp = S + (size_t)pair * NN * NN;
  const int tid  = threadIdx.x;
  const int lane = tid & 63;
  const int wv   = tid >> 6;

  __shared__ ull keys[CAPS];           // 16 KB: (desc-value key)<<32 | flat idx
  __shared__ float sub[64 * 65];       // 16.6 KB: compacted alive submatrix (phase 4)
  __shared__ int lcount;

  if (tid == 0) lcount = 0;
  __syncthreads();

  // ---- Phase 1: collect entries > THRESH ----
  const float4* S4 = (const float4*)Sp;
#pragma unroll 4
  for (int i4 = tid; i4 < NN*NN/4; i4 += 256) {
    float4 x = S4[i4];
    float xv[4] = {x.x, x.y, x.z, x.w};
#pragma unroll
    for (int e = 0; e < 4; ++e) {
      if (xv[e] > THRESH) {
        unsigned b = __float_as_uint(xv[e]);
        unsigned u = (b & 0x80000000u) ? ~b : (b | 0x80000000u);  // monotone asc
        int pos = atomicAdd(&lcount, 1);
        if (pos < CAPS)
          keys[pos] = ((ull)(~u) << 32) | (unsigned)(i4*4 + e);
      }
    }
  }
  __syncthreads();
  int count = lcount;
  if (count > CAPS) count = 0;         // overflow => full fallback (correct, slow)
  for (int i = count + tid; i < CAPS; i += 256) keys[i] = ~0ull;  // pad to end
  __syncthreads();

  // ---- Phase 2: bitonic sort ascending. Steps with compare distance < 512
  // are local to one wave's 512-element chunk: run them wave-synchronously
  // (in-order LDS pipe + wave_barrier), no __syncthreads. Only 3 cross-chunk
  // steps + transitions need block barriers.
#define CMPSWAP(I, K)                                                          \
  {                                                                            \
    unsigned ixj = (I) ^ j;                                                    \
    if (ixj > (I)) {                                                           \
      ull a = keys[(I)], b = keys[ixj];                                        \
      bool asc = (((I) & (K)) == 0);                                           \
      if ((a > b) == asc) { keys[(I)] = b; keys[ixj] = a; }                    \
    }                                                                          \
  }

  const unsigned wbase = wv * 512;
  // levels k=2..512: fully chunk-local
  for (unsigned k = 2; k <= 512; k <<= 1)
    for (unsigned j = k >> 1; j > 0; j >>= 1) {
      for (unsigned t = lane; t < 512; t += 64) { unsigned i = wbase + t; CMPSWAP(i, k) }
      __builtin_amdgcn_wave_barrier();
    }
  __syncthreads();
  // k=1024: j=512 crosses chunks
  {
    unsigned j = 512;
    for (unsigned i = tid; i < CAPS; i += 256) CMPSWAP(i, 1024)
  }
  __syncthreads();
  //         j=256..1 chunk-local
  for (unsigned j = 256; j > 0; j >>= 1) {
    for (unsigned t = lane; t < 512; t += 64) { unsigned i = wbase + t; CMPSWAP(i, 1024) }
    __builtin_amdgcn_wave_barrier();
  }
  __syncthreads();
  // k=2048: j=1024, j=512 cross chunks
  {
    unsigned j = 1024;
    for (unsigned i = tid; i < CAPS; i += 256) CMPSWAP(i, 2048)
  }
  __syncthreads();
  {
    unsigned j = 512;
    for (unsigned i = tid; i < CAPS; i += 256) CMPSWAP(i, 2048)
  }
  __syncthreads();
  //         j=256..1 chunk-local
  for (unsigned j = 256; j > 0; j >>= 1) {
    for (unsigned t = lane; t < 512; t += 64) { unsigned i = wbase + t; CMPSWAP(i, 2048) }
    __builtin_amdgcn_wave_barrier();
  }
  __syncthreads();
#undef CMPSWAP

  if (tid >= 64) return;               // waves 1..3 done; no barriers below

  // ---- Phase 3: ordered scan (wave 0). Masks wave-uniform in registers ----
  ull arow0 = ~0ull, arow1 = ~0ull, arow2 = ~0ull, arow3 = ~0ull;
  ull acol0 = ~0ull, acol1 = ~0ull, acol2 = ~0ull, acol3 = ~0ull;
  float sum = 0.0f;
  int picks = 0;

  for (int base = 0; base < count && picks < NN; base += 64) {
    const ull key = keys[base + lane];
    const int flat = (int)(unsigned)key;
    const int r = (flat >> 8) & 255, c = flat & 255;
    const unsigned u = ~(unsigned)(key >> 32);
    const float val = __uint_as_float((u & 0x80000000u) ? (u ^ 0x80000000u) : ~u);
    const bool valid = (base + lane) < count;

    int last = -1;
    while (true) {
      ull rs = (r & 128) ? ((r & 64) ? arow3 : arow2)
                         : ((r & 64) ? arow1 : arow0);
      ull cs = (c & 128) ? ((c & 64) ? acol3 : acol2)
                         : ((c & 64) ? acol1 : acol0);
      bool alive = valid && (lane > last) &&
                   ((rs >> (r & 63)) & 1ull) && ((cs >> (c & 63)) & 1ull);
      ull mb = __ballot(alive);
      if (!mb) break;
      const int t = __builtin_ctzll(mb);           // lowest lane = sorted order
      sum += rdlane_f(val, t);
      ++picks;
      const int r_t = __builtin_amdgcn_readlane(r, t);
      const int c_t = __builtin_amdgcn_readlane(c, t);
      {  // branch-free mask updates (wave-uniform -> SALU cselect chains)
        const ull rb  = 1ull << (r_t & 63);
        const int rs6 = r_t >> 6;
        arow0 &= ~((rs6 == 0) ? rb : 0ull);
        arow1 &= ~((rs6 == 1) ? rb : 0ull);
        arow2 &= ~((rs6 == 2) ? rb : 0ull);
        arow3 &= ~((rs6 == 3) ? rb : 0ull);
        const ull cb  = 1ull << (c_t & 63);
        const int cs6 = c_t >> 6;
        acol0 &= ~((cs6 == 0) ? cb : 0ull);
        acol1 &= ~((cs6 == 1) ? cb : 0ull);
        acol2 &= ~((cs6 == 2) ? cb : 0ull);
        acol3 &= ~((cs6 == 3) ? cb : 0ull);
      }
      last = t;
      if (picks == NN) break;
    }
  }

  // ---- Phase 4: exact greedy on the remaining alive submatrix ----
  if (picks < NN) {
    const int k = NN - picks;          // alive rows == alive cols == k
    if (k <= 64) {
      // -- fast path: compact k x k alive submatrix into LDS, finish in-wave --
      const int myRow = nth_set4(arow0, arow1, arow2, arow3, lane);
      const int myCol = nth_set4(acol0, acol1, acol2, acol3, lane);
      for (int i = 0; i < k; ++i) {    // coalesced-ish row gathers, pipelined
        const int ri = __builtin_amdgcn_readlane(myRow, i);
        float v = 0.0f;
        if (lane < k) v = Sp[(size_t)ri * NN + myCol];
        sub[i * 65 + lane] = v;
      }
      asm volatile("s_waitcnt lgkmcnt(0)" ::: "memory");
      __builtin_amdgcn_wave_barrier();

      const ull fullMask = (k == 64) ? ~0ull : ((1ull << k) - 1ull);
      ull rowAlive = fullMask, colAlive = fullMask;
      float rmv; int rac;
      row_max_lds(&sub[lane * 65], colAlive, rmv, rac);  // garbage rows masked later

      for (int it = 0; it < k; ++it) {
        float v = ((rowAlive >> lane) & 1ull) ? rmv : -INFINITY;
        int c = lane;
        dpp_argmax(v, c);              // tie-break lowest lane = lowest orig row
        const int rstar = __builtin_amdgcn_readlane(c, 63);
        sum += rdlane_f(v, 63);
        const int cstar = __builtin_amdgcn_readlane(rac, rstar);
        rowAlive &= ~(1ull << rstar);
        colAlive &= ~(1ull << cstar);
        // all stale rows rescan CONCURRENTLY (exec-masked), from LDS
        const bool stale = ((rowAlive >> lane) & 1ull) && (rac == cstar);
        if (__ballot(stale)) {
          if (stale) row_max_lds(&sub[lane * 65], colAlive, rmv, rac);
        }
      }
    } else {
      // -- slow exact path (candidate overflow / unusually long tail) --
      float rm[4]; int ra[4];
#pragma unroll
      for (int i = 0; i < 4; ++i) { rm[i] = -INFINITY; ra[i] = -1; }
#pragma unroll
      for (int i = 0; i < 4; ++i) {
        ull m = (i==0) ? arow0 : (i==1) ? arow1 : (i==2) ? arow2 : arow3;
        while (m) {
          const int l = __builtin_ctzll(m); m &= m - 1;
          float rv; int rc;
          rescan_row(Sp, i*64 + l, acol0, acol1, acol2, acol3, lane, rv, rc);
          if (lane == l) { rm[i] = rv; ra[i] = rc; }
        }
      }

      for (int it = picks; it < NN; ++it) {
        float v = rm[0]; int c = lane;
        if (rm[1] > v) { v = rm[1]; c = 64 + lane; }
        if (rm[2] > v) { v = rm[2]; c = 128 + lane; }
        if (rm[3] > v) { v = rm[3]; c = 192 + lane; }
        dpp_argmax(v, c);
        const int   br  = __builtin_amdgcn_readlane(c, 63);
        const float bvv = rdlane_f(v, 63);
        sum += bvv;

        const int bslot = br >> 6, blane = br & 63;
        int myra = ra[0];
        if (bslot == 1) myra = ra[1];
        if (bslot == 2) myra = ra[2];
        if (bslot == 3) myra = ra[3];
        const int bc = __builtin_amdgcn_readlane(myra, blane);

        if (lane == blane) {
          if (bslot == 0) { rm[0] = -INFINITY; ra[0] = -1; }
          if (bslot == 1) { rm[1] = -INFINITY; ra[1] = -1; }
          if (bslot == 2) { rm[2] = -INFINITY; ra[2] = -1; }
          if (bslot == 3) { rm[3] = -INFINITY; ra[3] = -1; }
        }
        const ull cb = ~(1ull << (bc & 63));
        if      (bc < 64)  acol0 &= cb;
        else if (bc < 128) acol1 &= cb;
        else if (bc < 192) acol2 &= cb;
        else               acol3 &= cb;

#pragma unroll
        for (int i = 0; i < 4; ++i) {
          ull m = __ballot(ra[i] == bc);
          while (m) {
            const int l = __builtin_ctzll(m); m &= m - 1;
            float rv; int rc;
            rescan_row(Sp, i*64 + l, acol0, acol1, acol2, acol3, lane, rv, rc);
            if (lane == l) { rm[i] = rv; ra[i] = rc; }
          }
        }
      }
    }
  }

  if (lane == 0) out[pair] = tanhf(sum / (float)NN);
}

extern "C" void kernel_launch(void* const* d_in, const int* in_sizes, int n_in,
                              void* d_out, int out_size, void* d_ws, size_t ws_size,
                              hipStream_t stream) {
  const float* x1 = (const float*)d_in[0];
  const float* x2 = (const float*)d_in[1];
  float* out = (float*)d_out;
  float* S   = (float*)d_ws;           // B*N*N*4 = 32 MiB

  const int B = in_sizes[0] / (NN * DD);

  dim3 ggrid(NN / 64, NN / 128, B);    // 4 x 2 x 128 = 1024 blocks
  gemm_bt_mfma<<<ggrid, 256, 0, stream>>>(x1, x2, S);
  sort_scan_match<<<B, 256, 0, stream>>>(S, out);
}

// Round 2
// 326.779 us; speedup vs baseline: 1.1748x; 1.1178x over previous
//
#include <hip/hip_runtime.h>
#include <cmath>

// MNEMatch: B pairs of [N,D] fp32; S = x1 @ x2^T per pair; greedy max matching
// (== sort entries desc + scan taking row/col-free entries); out[b]=tanh(sum/N).
#define NN 256
#define DD 384
#define CAPS 2048        // sorted candidate capacity (mean ~1350 at T=40, 19 sigma below CAPS)
#define THRESH 40.0f     // ~2.04 sigma of N(0,384)

typedef unsigned long long ull;
typedef short bf16x8 __attribute__((ext_vector_type(8)));
typedef float f32x4  __attribute__((ext_vector_type(4)));

// ---------------- Kernel 1: batched S = A @ B^T via bf16 MFMA --------------
__device__ __forceinline__ unsigned bfpack2(float lo, float hi) {
  return (__float_as_uint(hi) & 0xFFFF0000u) | (__float_as_uint(lo) >> 16);
}

__global__ __launch_bounds__(256) void gemm_bt_mfma(const float* __restrict__ X1,
                                                    const float* __restrict__ X2,
                                                    float* __restrict__ S) {
  const int pair  = blockIdx.z;
  const int rbase = blockIdx.y * 128;
  const int cbase = blockIdx.x * 64;

  __shared__ unsigned short As[128][40];  // 32 k-vals + pad
  __shared__ unsigned short Bs[64][40];

  const int tid   = threadIdx.x;
  const int lane  = tid & 63;
  const int wave  = tid >> 6;
  const int q     = lane >> 4, mi = lane & 15;

  const int srowA = tid >> 1, halfA = tid & 1;
  const int srowB = tid >> 2, qB    = tid & 3;

  const float* Abase = X1 + (size_t)pair * NN * DD + (size_t)(rbase + srowA) * DD + halfA * 16;
  const float* Bbase = X2 + (size_t)pair * NN * DD + (size_t)(cbase + srowB) * DD + qB * 8;

  f32x4 acc[2][4] = {};

  float4 pa0, pa1, pa2, pa3, pb0, pb1;
  {
    const float4* ap = (const float4*)(Abase);
    const float4* bp = (const float4*)(Bbase);
    pa0 = ap[0]; pa1 = ap[1]; pa2 = ap[2]; pa3 = ap[3];
    pb0 = bp[0]; pb1 = bp[1];
  }

  for (int k0 = 0; k0 < DD; k0 += 32) {
    __syncthreads();
    {
      uint4 w0 = make_uint4(bfpack2(pa0.x,pa0.y), bfpack2(pa0.z,pa0.w),
                            bfpack2(pa1.x,pa1.y), bfpack2(pa1.z,pa1.w));
      uint4 w1 = make_uint4(bfpack2(pa2.x,pa2.y), bfpack2(pa2.z,pa2.w),
                            bfpack2(pa3.x,pa3.y), bfpack2(pa3.z,pa3.w));
      *(uint4*)&As[srowA][halfA*16]     = w0;
      *(uint4*)&As[srowA][halfA*16 + 8] = w1;
      uint4 v0 = make_uint4(bfpack2(pb0.x,pb0.y), bfpack2(pb0.z,pb0.w),
                            bfpack2(pb1.x,pb1.y), bfpack2(pb1.z,pb1.w));
      *(uint4*)&Bs[srowB][qB*8] = v0;
    }
    __syncthreads();
    const int kn = k0 + 32;
    if (kn < DD) {
      const float4* ap = (const float4*)(Abase + kn);
      const float4* bp = (const float4*)(Bbase + kn);
      pa0 = ap[0]; pa1 = ap[1]; pa2 = ap[2]; pa3 = ap[3];
      pb0 = bp[0]; pb1 = bp[1];
    }
    bf16x8 af[2], bf[4];
#pragma unroll
    for (int i = 0; i < 2; ++i) af[i] = *(const bf16x8*)&As[wave*32 + i*16 + mi][q*8];
#pragma unroll
    for (int j = 0; j < 4; ++j) bf[j] = *(const bf16x8*)&Bs[j*16 + mi][q*8];
#pragma unroll
    for (int i = 0; i < 2; ++i)
#pragma unroll
      for (int j = 0; j < 4; ++j)
        acc[i][j] = __builtin_amdgcn_mfma_f32_16x16x32_bf16(af[i], bf[j], acc[i][j], 0, 0, 0);
  }

  float* Sp = S + (size_t)pair * NN * NN;
#pragma unroll
  for (int i = 0; i < 2; ++i)
#pragma unroll
    for (int j = 0; j < 4; ++j)
#pragma unroll
      for (int r2 = 0; r2 < 4; ++r2) {
        const int rowg = rbase + wave*32 + i*16 + q*4 + r2;
        const int colg = cbase + j*16 + mi;
        Sp[(size_t)rowg * NN + colg] = acc[i][j][r2];
      }
}

// ---------------- DPP wave64 argmax (result in lane 63) --------------------
#define DPP_STEP(ctrl, rmask)                                                  \
  {                                                                            \
    int vi  = __float_as_int(v);                                               \
    int v2b = __builtin_amdgcn_update_dpp(vi, vi, (ctrl), (rmask), 0xf, false);\
    int i2  = __builtin_amdgcn_update_dpp(c,  c,  (ctrl), (rmask), 0xf, false);\
    float v2 = __int_as_float(v2b);                                            \
    if (v2 > v || (v2 == v && i2 < c)) { v = v2; c = i2; }                     \
  }

__device__ __forceinline__ void dpp_argmax(float& v, int& c) {
  DPP_STEP(0x111, 0xf)  // row_shr:1
  DPP_STEP(0x112, 0xf)  // row_shr:2
  DPP_STEP(0x114, 0xf)  // row_shr:4
  DPP_STEP(0x118, 0xf)  // row_shr:8
  DPP_STEP(0x142, 0xa)  // row_bcast:15
  DPP_STEP(0x143, 0xc)  // row_bcast:31
}
#undef DPP_STEP

__device__ __forceinline__ float rdlane_f(float v, int l) {
  return __int_as_float(__builtin_amdgcn_readlane(__float_as_int(v), l));
}

// masked full-row argmax over alive cols (slow exact path, k > 64 only)
__device__ __forceinline__ void rescan_row(const float* __restrict__ Sp, int r,
                                           ull a0, ull a1, ull a2, ull a3,
                                           int lane, float& rv, int& rc) {
  float v = -INFINITY; int c = -1;
#pragma unroll
  for (int j = 0; j < 4; ++j) {
    const int cc = j*64 + lane;
    float x = Sp[(size_t)r * NN + cc];
    ull aj = (j==0) ? a0 : (j==1) ? a1 : (j==2) ? a2 : a3;
    float mv = ((aj >> lane) & 1ull) ? x : -INFINITY;
    if (mv > v) { v = mv; c = cc; }
  }
  dpp_argmax(v, c);
  rv = rdlane_f(v, 63);
  rc = __builtin_amdgcn_readlane(c, 63);
}

// i-th set bit (ascending) of a 256-bit mask; 0 if fewer than i+1 bits set
__device__ __forceinline__ int nth_set4(ull m0, ull m1, ull m2, ull m3, int n) {
  int base = 0; ull m = m0;
  int c = __popcll(m);
  if (n >= c) { n -= c; m = m1; base = 64; c = __popcll(m);
    if (n >= c) { n -= c; m = m2; base = 128; c = __popcll(m);
      if (n >= c) { n -= c; m = m3; base = 192; } } }
  for (int i = 0; i < n; ++i) m &= m - 1;
  return m ? (base + (int)__builtin_ctzll(m)) : 0;
}

// max+argmax over one compacted LDS row, cols masked by colAlive.
__device__ __forceinline__ void row_max_lds(const float* __restrict__ rowp,
                                            ull colAlive, float& rmv, int& rac) {
  float m0 = -INFINITY, m1 = -INFINITY, m2 = -INFINITY, m3 = -INFINITY;
  int   a0 = 0, a1 = 1, a2 = 2, a3 = 3;
#pragma unroll
  for (int j = 0; j < 64; j += 4) {
    const unsigned g = (unsigned)(colAlive >> j);
    float x0 = (g & 1u) ? rowp[j]     : -INFINITY;
    float x1 = (g & 2u) ? rowp[j + 1] : -INFINITY;
    float x2 = (g & 4u) ? rowp[j + 2] : -INFINITY;
    float x3 = (g & 8u) ? rowp[j + 3] : -INFINITY;
    if (x0 > m0) { m0 = x0; a0 = j; }
    if (x1 > m1) { m1 = x1; a1 = j + 1; }
    if (x2 > m2) { m2 = x2; a2 = j + 2; }
    if (x3 > m3) { m3 = x3; a3 = j + 3; }
  }
  float mv = m0; int ai = a0;
  if (m1 > mv) { mv = m1; ai = a1; }
  if (m2 > mv) { mv = m2; ai = a2; }
  if (m3 > mv) { mv = m3; ai = a3; }
  rmv = mv; rac = ai;
}

// ---- Phase 4: exact greedy on the remaining alive submatrix (one wave) ----
__device__ float finish_tail(const float* __restrict__ Sp, float* __restrict__ sub,
                             int lane,
                             ull arow0, ull arow1, ull arow2, ull arow3,
                             ull acol0, ull acol1, ull acol2, ull acol3,
                             int picks, float sum) {
  if (picks >= NN) return sum;
  const int k = NN - picks;            // alive rows == alive cols == k
  if (k <= 64) {
    // fast path: compact k x k alive submatrix into LDS, finish in-wave
    const int myRow = nth_set4(arow0, arow1, arow2, arow3, lane);
    const int myCol = nth_set4(acol0, acol1, acol2, acol3, lane);
    for (int i = 0; i < k; ++i) {
      const int ri = __builtin_amdgcn_readlane(myRow, i);
      float v = 0.0f;
      if (lane < k) v = Sp[(size_t)ri * NN + myCol];
      sub[i * 65 + lane] = v;
    }
    asm volatile("s_waitcnt lgkmcnt(0)" ::: "memory");
    __builtin_amdgcn_wave_barrier();

    const ull fullMask = (k == 64) ? ~0ull : ((1ull << k) - 1ull);
    ull rowAlive = fullMask, colAlive = fullMask;
    float rmv; int rac;
    row_max_lds(&sub[lane * 65], colAlive, rmv, rac);

    for (int it = 0; it < k; ++it) {
      float v = ((rowAlive >> lane) & 1ull) ? rmv : -INFINITY;
      int c = lane;
      dpp_argmax(v, c);
      const int rstar = __builtin_amdgcn_readlane(c, 63);
      sum += rdlane_f(v, 63);
      const int cstar = __builtin_amdgcn_readlane(rac, rstar);
      rowAlive &= ~(1ull << rstar);
      colAlive &= ~(1ull << cstar);
      const bool stale = ((rowAlive >> lane) & 1ull) && (rac == cstar);
      if (__ballot(stale)) {
        if (stale) row_max_lds(&sub[lane * 65], colAlive, rmv, rac);
      }
    }
  } else {
    // slow exact path (candidate overflow / unusually long tail)
    float rm[4]; int ra[4];
#pragma unroll
    for (int i = 0; i < 4; ++i) { rm[i] = -INFINITY; ra[i] = -1; }
#pragma unroll
    for (int i = 0; i < 4; ++i) {
      ull m = (i==0) ? arow0 : (i==1) ? arow1 : (i==2) ? arow2 : arow3;
      while (m) {
        const int l = __builtin_ctzll(m); m &= m - 1;
        float rv; int rc;
        rescan_row(Sp, i*64 + l, acol0, acol1, acol2, acol3, lane, rv, rc);
        if (lane == l) { rm[i] = rv; ra[i] = rc; }
      }
    }

    for (int it = picks; it < NN; ++it) {
      float v = rm[0]; int c = lane;
      if (rm[1] > v) { v = rm[1]; c = 64 + lane; }
      if (rm[2] > v) { v = rm[2]; c = 128 + lane; }
      if (rm[3] > v) { v = rm[3]; c = 192 + lane; }
      dpp_argmax(v, c);
      const int   br  = __builtin_amdgcn_readlane(c, 63);
      const float bvv = rdlane_f(v, 63);
      sum += bvv;

      const int bslot = br >> 6, blane = br & 63;
      int myra = ra[0];
      if (bslot == 1) myra = ra[1];
      if (bslot == 2) myra = ra[2];
      if (bslot == 3) myra = ra[3];
      const int bc = __builtin_amdgcn_readlane(myra, blane);

      if (lane == blane) {
        if (bslot == 0) { rm[0] = -INFINITY; ra[0] = -1; }
        if (bslot == 1) { rm[1] = -INFINITY; ra[1] = -1; }
        if (bslot == 2) { rm[2] = -INFINITY; ra[2] = -1; }
        if (bslot == 3) { rm[3] = -INFINITY; ra[3] = -1; }
      }
      const ull cb = ~(1ull << (bc & 63));
      if      (bc < 64)  acol0 &= cb;
      else if (bc < 128) acol1 &= cb;
      else if (bc < 192) acol2 &= cb;
      else               acol3 &= cb;

#pragma unroll
      for (int i = 0; i < 4; ++i) {
        ull m = __ballot(ra[i] == bc);
        while (m) {
          const int l = __builtin_ctzll(m); m &= m - 1;
          float rv; int rc;
          rescan_row(Sp, i*64 + l, acol0, acol1, acol2, acol3, lane, rv, rc);
          if (lane == l) { rm[i] = rv; ra[i] = rc; }
        }
      }
    }
  }
  return sum;
}

// ------ Kernel 2a: collect + bitonic sort (8 waves), keys -> global --------
__global__ __launch_bounds__(512) void collect_sort(const float* __restrict__ S,
                                                    ull* __restrict__ gkeys,
                                                    int* __restrict__ gcnt) {
  const int pair = blockIdx.x;
  const float* Sp = S + (size_t)pair * NN * NN;
  const int tid  = threadIdx.x;
  const int lane = tid & 63;
  const int wv   = tid >> 6;

  __shared__ ull keys[CAPS];           // 16 KB
  __shared__ int lcount;
  if (tid == 0) lcount = 0;
  __syncthreads();

  // ---- collect entries > THRESH ----
  const float4* S4 = (const float4*)Sp;
#pragma unroll 4
  for (int i4 = tid; i4 < NN*NN/4; i4 += 512) {
    float4 x = S4[i4];
    float xv[4] = {x.x, x.y, x.z, x.w};
#pragma unroll
    for (int e = 0; e < 4; ++e) {
      if (xv[e] > THRESH) {
        unsigned b = __float_as_uint(xv[e]);
        unsigned u = (b & 0x80000000u) ? ~b : (b | 0x80000000u);  // monotone asc
        int pos = atomicAdd(&lcount, 1);
        if (pos < CAPS)
          keys[pos] = ((ull)(~u) << 32) | (unsigned)(i4*4 + e);
      }
    }
  }
  __syncthreads();
  int count = lcount;
  if (count > CAPS) count = 0;         // overflow => full fallback downstream
  for (int i = count + tid; i < CAPS; i += 512) keys[i] = ~0ull;
  __syncthreads();

  // ---- bitonic sort ascending; wave-local 256-elem chunks ----
#define CMPSWAP(I, K)                                                          \
  {                                                                            \
    unsigned ixj = (I) ^ j;                                                    \
    if (ixj > (I)) {                                                           \
      ull a = keys[(I)], b = keys[ixj];                                        \
      bool asc = (((I) & (K)) == 0);                                           \
      if ((a > b) == asc) { keys[(I)] = b; keys[ixj] = a; }                    \
    }                                                                          \
  }

  const unsigned wbase = wv * 256;
  for (unsigned k = 2; k <= 256; k <<= 1)
    for (unsigned j = k >> 1; j > 0; j >>= 1) {
      for (unsigned t = lane; t < 256; t += 64) { unsigned i = wbase + t; CMPSWAP(i, k) }
      __builtin_amdgcn_wave_barrier();
    }
  __syncthreads();
  // k=512: j=256 cross, then local
  { unsigned j = 256; for (unsigned i = tid; i < CAPS; i += 512) CMPSWAP(i, 512) }
  __syncthreads();
  for (unsigned j = 128; j > 0; j >>= 1) {
    for (unsigned t = lane; t < 256; t += 64) { unsigned i = wbase + t; CMPSWAP(i, 512) }
    __builtin_amdgcn_wave_barrier();
  }
  __syncthreads();
  // k=1024: j=512,256 cross, then local
  { unsigned j = 512; for (unsigned i = tid; i < CAPS; i += 512) CMPSWAP(i, 1024) }
  __syncthreads();
  { unsigned j = 256; for (unsigned i = tid; i < CAPS; i += 512) CMPSWAP(i, 1024) }
  __syncthreads();
  for (unsigned j = 128; j > 0; j >>= 1) {
    for (unsigned t = lane; t < 256; t += 64) { unsigned i = wbase + t; CMPSWAP(i, 1024) }
    __builtin_amdgcn_wave_barrier();
  }
  __syncthreads();
  // k=2048: j=1024,512,256 cross, then local
  { unsigned j = 1024; for (unsigned i = tid; i < CAPS; i += 512) CMPSWAP(i, 2048) }
  __syncthreads();
  { unsigned j = 512; for (unsigned i = tid; i < CAPS; i += 512) CMPSWAP(i, 2048) }
  __syncthreads();
  { unsigned j = 256; for (unsigned i = tid; i < CAPS; i += 512) CMPSWAP(i, 2048) }
  __syncthreads();
  for (unsigned j = 128; j > 0; j >>= 1) {
    for (unsigned t = lane; t < 256; t += 64) { unsigned i = wbase + t; CMPSWAP(i, 2048) }
    __builtin_amdgcn_wave_barrier();
  }
#undef CMPSWAP
  __syncthreads();

  for (int i = tid; i < count; i += 512) gkeys[(size_t)pair * CAPS + i] = keys[i];
  if (tid == 0) gcnt[pair] = count;
}

// ------ Kernel 2b: ordered scan + tail greedy, 1 wave per pair -------------
__global__ __launch_bounds__(64) void scan_match(const float* __restrict__ S,
                                                 const ull* __restrict__ gkeys,
                                                 const int* __restrict__ gcnt,
                                                 float* __restrict__ out) {
  const int pair = blockIdx.x;
  const float* Sp = S + (size_t)pair * NN * NN;
  const int lane = threadIdx.x;

  __shared__ float sub[64 * 65];       // 16.6 KB, phase-4 fast path

  const int count = gcnt[pair];
  const ull* kp = gkeys + (size_t)pair * CAPS;

  ull arow0 = ~0ull, arow1 = ~0ull, arow2 = ~0ull, arow3 = ~0ull;
  ull acol0 = ~0ull, acol1 = ~0ull, acol2 = ~0ull, acol3 = ~0ull;
  float sum = 0.0f;
  int picks = 0;

  // prefetch first batch
  ull key = ~0ull;
  if (count > 0) { int i0 = (lane < count) ? lane : 0; key = kp[i0]; }

  for (int base = 0; base < count && picks < NN; base += 64) {
    // issue next batch's load before processing current (hides latency)
    ull nkey = ~0ull;
    const int nbase = base + 64;
    if (nbase < count) { int ni = nbase + lane; if (ni >= count) ni = nbase; nkey = kp[ni]; }

    const int flat = (int)(unsigned)key;
    const int r = (flat >> 8) & 255, c = flat & 255;
    const unsigned u = ~(unsigned)(key >> 32);
    const float val = __uint_as_float((u & 0x80000000u) ? (u ^ 0x80000000u) : ~u);
    const bool valid = (base + lane) < count;

    // init per-lane alive from the wave-uniform masks (once per batch)
    const ull rs = (r & 128) ? ((r & 64) ? arow3 : arow2) : ((r & 64) ? arow1 : arow0);
    const ull cs = (c & 128) ? ((c & 64) ? acol3 : acol2) : ((c & 64) ? acol1 : acol0);
    bool alive = valid && (((rs >> (r & 63)) & 1ull) != 0) && (((cs >> (c & 63)) & 1ull) != 0);

    // per-pick recurrence: ballot -> ctz -> readlane -> compare-kill
    while (true) {
      const ull mb = __ballot(alive);
      if (!mb) break;
      const int t   = __builtin_ctzll(mb);       // lowest lane = sorted order
      const int r_t = __builtin_amdgcn_readlane(r, t);
      const int c_t = __builtin_amdgcn_readlane(c, t);
      sum += rdlane_f(val, t);
      ++picks;
      alive = alive && (r != r_t) && (c != c_t);
      { // SGPR mask bookkeeping — off the critical recurrence
        const ull rb = 1ull << (r_t & 63); const int rs6 = r_t >> 6;
        arow0 &= ~((rs6 == 0) ? rb : 0ull);
        arow1 &= ~((rs6 == 1) ? rb : 0ull);
        arow2 &= ~((rs6 == 2) ? rb : 0ull);
        arow3 &= ~((rs6 == 3) ? rb : 0ull);
        const ull cb = 1ull << (c_t & 63); const int cs6 = c_t >> 6;
        acol0 &= ~((cs6 == 0) ? cb : 0ull);
        acol1 &= ~((cs6 == 1) ? cb : 0ull);
        acol2 &= ~((cs6 == 2) ? cb : 0ull);
        acol3 &= ~((cs6 == 3) ? cb : 0ull);
      }
      if (picks == NN) break;
    }
    key = nkey;
  }

  sum = finish_tail(Sp, sub, lane, arow0, arow1, arow2, arow3,
                    acol0, acol1, acol2, acol3, picks, sum);

  if (lane == 0) out[pair] = tanhf(sum / (float)NN);
}

// ------ Fused fallback (used only if workspace can't fit the keys) ---------
__global__ __launch_bounds__(256) void sort_scan_match(const float* __restrict__ S,
                                                       float* __restrict__ out) {
  const int pair = blockIdx.x;
  const float* Sp = S + (size_t)pair * NN * NN;
  const int tid  = threadIdx.x;
  const int lane = tid & 63;
  const int wv   = tid >> 6;

  __shared__ ull keys[CAPS];
  __shared__ float sub[64 * 65];
  __shared__ int lcount;

  if (tid == 0) lcount = 0;
  __syncthreads();

  const float4* S4 = (const float4*)Sp;
#pragma unroll 4
  for (int i4 = tid; i4 < NN*NN/4; i4 += 256) {
    float4 x = S4[i4];
    float xv[4] = {x.x, x.y, x.z, x.w};
#pragma unroll
    for (int e = 0; e < 4; ++e) {
      if (xv[e] > THRESH) {
        unsigned b = __float_as_uint(xv[e]);
        unsigned u = (b & 0x80000000u) ? ~b : (b | 0x80000000u);
        int pos = atomicAdd(&lcount, 1);
        if (pos < CAPS)
          keys[pos] = ((ull)(~u) << 32) | (unsigned)(i4*4 + e);
      }
    }
  }
  __syncthreads();
  int count = lcount;
  if (count > CAPS) count = 0;
  for (int i = count + tid; i < CAPS; i += 256) keys[i] = ~0ull;
  __syncthreads();

#define CMPSWAP(I, K)                                                          \
  {                                                                            \
    unsigned ixj = (I) ^ j;                                                    \
    if (ixj > (I)) {                                                           \
      ull a = keys[(I)], b = keys[ixj];                                        \
      bool asc = (((I) & (K)) == 0);                                           \
      if ((a > b) == asc) { keys[(I)] = b; keys[ixj] = a; }                    \
    }                                                                          \
  }
  const unsigned wbase = wv * 512;
  for (unsigned k = 2; k <= 512; k <<= 1)
    for (unsigned j = k >> 1; j > 0; j >>= 1) {
      for (unsigned t = lane; t < 512; t += 64) { unsigned i = wbase + t; CMPSWAP(i, k) }
      __builtin_amdgcn_wave_barrier();
    }
  __syncthreads();
  { unsigned j = 512; for (unsigned i = tid; i < CAPS; i += 256) CMPSWAP(i, 1024) }
  __syncthreads();
  for (unsigned j = 256; j > 0; j >>= 1) {
    for (unsigned t = lane; t < 512; t += 64) { unsigned i = wbase + t; CMPSWAP(i, 1024) }
    __builtin_amdgcn_wave_barrier();
  }
  __syncthreads();
  { unsigned j = 1024; for (unsigned i = tid; i < CAPS; i += 256) CMPSWAP(i, 2048) }
  __syncthreads();
  { unsigned j = 512; for (unsigned i = tid; i < CAPS; i += 256) CMPSWAP(i, 2048) }
  __syncthreads();
  for (unsigned j = 256; j > 0; j >>= 1) {
    for (unsigned t = lane; t < 512; t += 64) { unsigned i = wbase + t; CMPSWAP(i, 2048) }
    __builtin_amdgcn_wave_barrier();
  }
  __syncthreads();
#undef CMPSWAP

  if (tid >= 64) return;

  ull arow0 = ~0ull, arow1 = ~0ull, arow2 = ~0ull, arow3 = ~0ull;
  ull acol0 = ~0ull, acol1 = ~0ull, acol2 = ~0ull, acol3 = ~0ull;
  float sum = 0.0f;
  int picks = 0;

  for (int base = 0; base < count && picks < NN; base += 64) {
    const ull key = keys[base + lane];
    const int flat = (int)(unsigned)key;
    const int r = (flat >> 8) & 255, c = flat & 255;
    const unsigned u = ~(unsigned)(key >> 32);
    const float val = __uint_as_float((u & 0x80000000u) ? (u ^ 0x80000000u) : ~u);
    const bool valid = (base + lane) < count;

    const ull rs = (r & 128) ? ((r & 64) ? arow3 : arow2) : ((r & 64) ? arow1 : arow0);
    const ull cs = (c & 128) ? ((c & 64) ? acol3 : acol2) : ((c & 64) ? acol1 : acol0);
    bool alive = valid && (((rs >> (r & 63)) & 1ull) != 0) && (((cs >> (c & 63)) & 1ull) != 0);

    while (true) {
      const ull mb = __ballot(alive);
      if (!mb) break;
      const int t   = __builtin_ctzll(mb);
      const int r_t = __builtin_amdgcn_readlane(r, t);
      const int c_t = __builtin_amdgcn_readlane(c, t);
      sum += rdlane_f(val, t);
      ++picks;
      alive = alive && (r != r_t) && (c != c_t);
      {
        const ull rb = 1ull << (r_t & 63); const int rs6 = r_t >> 6;
        arow0 &= ~((rs6 == 0) ? rb : 0ull);
        arow1 &= ~((rs6 == 1) ? rb : 0ull);
        arow2 &= ~((rs6 == 2) ? rb : 0ull);
        arow3 &= ~((rs6 == 3) ? rb : 0ull);
        const ull cb = 1ull << (c_t & 63); const int cs6 = c_t >> 6;
        acol0 &= ~((cs6 == 0) ? cb : 0ull);
        acol1 &= ~((cs6 == 1) ? cb : 0ull);
        acol2 &= ~((cs6 == 2) ? cb : 0ull);
        acol3 &= ~((cs6 == 3) ? cb : 0ull);
      }
      if (picks == NN) break;
    }
  }

  sum = finish_tail(Sp, sub, lane, arow0, arow1, arow2, arow3,
                    acol0, acol1, acol2, acol3, picks, sum);

  if (lane == 0) out[pair] = tanhf(sum / (float)NN);
}

extern "C" void kernel_launch(void* const* d_in, const int* in_sizes, int n_in,
                              void* d_out, int out_size, void* d_ws, size_t ws_size,
                              hipStream_t stream) {
  const float* x1 = (const float*)d_in[0];
  const float* x2 = (const float*)d_in[1];
  float* out = (float*)d_out;
  float* S   = (float*)d_ws;           // B*N*N*4 = 32 MiB

  const int B = in_sizes[0] / (NN * DD);

  ull* gkeys = (ull*)(S + (size_t)B * NN * NN);       // B*CAPS*8 = 2 MiB
  int* gcnt  = (int*)(gkeys + (size_t)B * CAPS);      // B*4
  const size_t need = (size_t)B * NN * NN * 4 + (size_t)B * CAPS * 8 + (size_t)B * 4;

  dim3 ggrid(NN / 64, NN / 128, B);    // 4 x 2 x 128 = 1024 blocks
  gemm_bt_mfma<<<ggrid, 256, 0, stream>>>(x1, x2, S);

  if (ws_size >= need) {
    collect_sort<<<B, 512, 0, stream>>>(S, gkeys, gcnt);
    scan_match<<<B, 64, 0, stream>>>(S, gkeys, gcnt, out);
  } else {
    sort_scan_match<<<B, 256, 0, stream>>>(S, out);   // fused fallback
  }
}

// Round 3
// 306.570 us; speedup vs baseline: 1.2523x; 1.0659x over previous
//
#include <hip/hip_runtime.h>
#include <cmath>

// MNEMatch: B pairs of [N,D] fp32; S = x1 @ x2^T per pair; greedy max matching
// (== sort entries desc + scan taking row/col-free entries); out[b]=tanh(sum/N).
#define NN 256
#define DD 384
#define CAPS 2048        // sorted candidate capacity (mean ~1350 at T=40, 19 sigma below CAPS)
#define THRESH 40.0f     // ~2.04 sigma of N(0,384)

typedef unsigned long long ull;
typedef short bf16x8 __attribute__((ext_vector_type(8)));
typedef float f32x4  __attribute__((ext_vector_type(4)));

// ---------------- Kernel 1: batched S = A @ B^T via bf16 MFMA --------------
__device__ __forceinline__ unsigned bfpack2(float lo, float hi) {
  return (__float_as_uint(hi) & 0xFFFF0000u) | (__float_as_uint(lo) >> 16);
}

__global__ __launch_bounds__(256) void gemm_bt_mfma(const float* __restrict__ X1,
                                                    const float* __restrict__ X2,
                                                    float* __restrict__ S) {
  const int pair  = blockIdx.z;
  const int rbase = blockIdx.y * 128;
  const int cbase = blockIdx.x * 64;

  __shared__ unsigned short As[128][40];  // 32 k-vals + pad
  __shared__ unsigned short Bs[64][40];

  const int tid   = threadIdx.x;
  const int lane  = tid & 63;
  const int wave  = tid >> 6;
  const int q     = lane >> 4, mi = lane & 15;

  const int srowA = tid >> 1, halfA = tid & 1;
  const int srowB = tid >> 2, qB    = tid & 3;

  const float* Abase = X1 + (size_t)pair * NN * DD + (size_t)(rbase + srowA) * DD + halfA * 16;
  const float* Bbase = X2 + (size_t)pair * NN * DD + (size_t)(cbase + srowB) * DD + qB * 8;

  f32x4 acc[2][4] = {};

  float4 pa0, pa1, pa2, pa3, pb0, pb1;
  {
    const float4* ap = (const float4*)(Abase);
    const float4* bp = (const float4*)(Bbase);
    pa0 = ap[0]; pa1 = ap[1]; pa2 = ap[2]; pa3 = ap[3];
    pb0 = bp[0]; pb1 = bp[1];
  }

  for (int k0 = 0; k0 < DD; k0 += 32) {
    __syncthreads();
    {
      uint4 w0 = make_uint4(bfpack2(pa0.x,pa0.y), bfpack2(pa0.z,pa0.w),
                            bfpack2(pa1.x,pa1.y), bfpack2(pa1.z,pa1.w));
      uint4 w1 = make_uint4(bfpack2(pa2.x,pa2.y), bfpack2(pa2.z,pa2.w),
                            bfpack2(pa3.x,pa3.y), bfpack2(pa3.z,pa3.w));
      *(uint4*)&As[srowA][halfA*16]     = w0;
      *(uint4*)&As[srowA][halfA*16 + 8] = w1;
      uint4 v0 = make_uint4(bfpack2(pb0.x,pb0.y), bfpack2(pb0.z,pb0.w),
                            bfpack2(pb1.x,pb1.y), bfpack2(pb1.z,pb1.w));
      *(uint4*)&Bs[srowB][qB*8] = v0;
    }
    __syncthreads();
    const int kn = k0 + 32;
    if (kn < DD) {
      const float4* ap = (const float4*)(Abase + kn);
      const float4* bp = (const float4*)(Bbase + kn);
      pa0 = ap[0]; pa1 = ap[1]; pa2 = ap[2]; pa3 = ap[3];
      pb0 = bp[0]; pb1 = bp[1];
    }
    bf16x8 af[2], bf[4];
#pragma unroll
    for (int i = 0; i < 2; ++i) af[i] = *(const bf16x8*)&As[wave*32 + i*16 + mi][q*8];
#pragma unroll
    for (int j = 0; j < 4; ++j) bf[j] = *(const bf16x8*)&Bs[j*16 + mi][q*8];
#pragma unroll
    for (int i = 0; i < 2; ++i)
#pragma unroll
      for (int j = 0; j < 4; ++j)
        acc[i][j] = __builtin_amdgcn_mfma_f32_16x16x32_bf16(af[i], bf[j], acc[i][j], 0, 0, 0);
  }

  float* Sp = S + (size_t)pair * NN * NN;
#pragma unroll
  for (int i = 0; i < 2; ++i)
#pragma unroll
    for (int j = 0; j < 4; ++j)
#pragma unroll
      for (int r2 = 0; r2 < 4; ++r2) {
        const int rowg = rbase + wave*32 + i*16 + q*4 + r2;
        const int colg = cbase + j*16 + mi;
        Sp[(size_t)rowg * NN + colg] = acc[i][j][r2];
      }
}

// ---------------- DPP wave64 argmax (result in lane 63) --------------------
#define DPP_STEP(ctrl, rmask)                                                  \
  {                                                                            \
    int vi  = __float_as_int(v);                                               \
    int v2b = __builtin_amdgcn_update_dpp(vi, vi, (ctrl), (rmask), 0xf, false);\
    int i2  = __builtin_amdgcn_update_dpp(c,  c,  (ctrl), (rmask), 0xf, false);\
    float v2 = __int_as_float(v2b);                                            \
    if (v2 > v || (v2 == v && i2 < c)) { v = v2; c = i2; }                     \
  }

__device__ __forceinline__ void dpp_argmax(float& v, int& c) {
  DPP_STEP(0x111, 0xf)  // row_shr:1
  DPP_STEP(0x112, 0xf)  // row_shr:2
  DPP_STEP(0x114, 0xf)  // row_shr:4
  DPP_STEP(0x118, 0xf)  // row_shr:8
  DPP_STEP(0x142, 0xa)  // row_bcast:15
  DPP_STEP(0x143, 0xc)  // row_bcast:31
}
#undef DPP_STEP

__device__ __forceinline__ float rdlane_f(float v, int l) {
  return __int_as_float(__builtin_amdgcn_readlane(__float_as_int(v), l));
}

// masked full-row argmax over alive cols (fused-fallback slow path only)
__device__ __forceinline__ void rescan_row(const float* __restrict__ Sp, int r,
                                           ull a0, ull a1, ull a2, ull a3,
                                           int lane, float& rv, int& rc) {
  float v = -INFINITY; int c = -1;
#pragma unroll
  for (int j = 0; j < 4; ++j) {
    const int cc = j*64 + lane;
    float x = Sp[(size_t)r * NN + cc];
    ull aj = (j==0) ? a0 : (j==1) ? a1 : (j==2) ? a2 : a3;
    float mv = ((aj >> lane) & 1ull) ? x : -INFINITY;
    if (mv > v) { v = mv; c = cc; }
  }
  dpp_argmax(v, c);
  rv = rdlane_f(v, 63);
  rc = __builtin_amdgcn_readlane(c, 63);
}

// i-th set bit (ascending) of a 256-bit mask; 0 if fewer than i+1 bits set
__device__ __forceinline__ int nth_set4(ull m0, ull m1, ull m2, ull m3, int n) {
  int base = 0; ull m = m0;
  int c = __popcll(m);
  if (n >= c) { n -= c; m = m1; base = 64; c = __popcll(m);
    if (n >= c) { n -= c; m = m2; base = 128; c = __popcll(m);
      if (n >= c) { n -= c; m = m3; base = 192; } } }
  for (int i = 0; i < n; ++i) m &= m - 1;
  return m ? (base + (int)__builtin_ctzll(m)) : 0;
}

// max+argmax over one compacted LDS row, cols masked by colAlive.
__device__ __forceinline__ void row_max_lds(const float* __restrict__ rowp,
                                            ull colAlive, float& rmv, int& rac) {
  float m0 = -INFINITY, m1 = -INFINITY, m2 = -INFINITY, m3 = -INFINITY;
  int   a0 = 0, a1 = 1, a2 = 2, a3 = 3;
#pragma unroll
  for (int j = 0; j < 64; j += 4) {
    const unsigned g = (unsigned)(colAlive >> j);
    float x0 = (g & 1u) ? rowp[j]     : -INFINITY;
    float x1 = (g & 2u) ? rowp[j + 1] : -INFINITY;
    float x2 = (g & 4u) ? rowp[j + 2] : -INFINITY;
    float x3 = (g & 8u) ? rowp[j + 3] : -INFINITY;
    if (x0 > m0) { m0 = x0; a0 = j; }
    if (x1 > m1) { m1 = x1; a1 = j + 1; }
    if (x2 > m2) { m2 = x2; a2 = j + 2; }
    if (x3 > m3) { m3 = x3; a3 = j + 3; }
  }
  float mv = m0; int ai = a0;
  if (m1 > mv) { mv = m1; ai = a1; }
  if (m2 > mv) { mv = m2; ai = a2; }
  if (m3 > mv) { mv = m3; ai = a3; }
  rmv = mv; rac = ai;
}

// per-lane scan of its OWN row over alive cols (wave-uniform masks -> SALU skip)
__device__ __forceinline__ void scan_own_row(const float* __restrict__ rowp,
                                             ull a0, ull a1, ull a2, ull a3,
                                             float& mv, int& ac) {
  float v = -INFINITY; int c = 0;
#pragma unroll
  for (int g = 0; g < 4; ++g) {
    const ull am = (g==0) ? a0 : (g==1) ? a1 : (g==2) ? a2 : a3;
#pragma unroll 8
    for (int j = 0; j < 64; ++j) {
      if ((am >> j) & 1ull) {
        const float x = rowp[g*64 + j];
        if (x > v) { v = x; c = g*64 + j; }
      }
    }
  }
  mv = v; ac = c;
}

// ---- legacy tail (fused fallback only): serial gather + global rescans ----
__device__ float finish_tail(const float* __restrict__ Sp, float* __restrict__ sub,
                             int lane,
                             ull arow0, ull arow1, ull arow2, ull arow3,
                             ull acol0, ull acol1, ull acol2, ull acol3,
                             int picks, float sum) {
  if (picks >= NN) return sum;
  const int k = NN - picks;
  if (k <= 64) {
    const int myRow = nth_set4(arow0, arow1, arow2, arow3, lane);
    const int myCol = nth_set4(acol0, acol1, acol2, acol3, lane);
    for (int i = 0; i < k; ++i) {
      const int ri = __builtin_amdgcn_readlane(myRow, i);
      float v = 0.0f;
      if (lane < k) v = Sp[(size_t)ri * NN + myCol];
      sub[i * 65 + lane] = v;
    }
    asm volatile("s_waitcnt lgkmcnt(0)" ::: "memory");
    __builtin_amdgcn_wave_barrier();

    const ull fullMask = (k == 64) ? ~0ull : ((1ull << k) - 1ull);
    ull rowAlive = fullMask, colAlive = fullMask;
    float rmv; int rac;
    row_max_lds(&sub[lane * 65], colAlive, rmv, rac);

    for (int it = 0; it < k; ++it) {
      float v = ((rowAlive >> lane) & 1ull) ? rmv : -INFINITY;
      int c = lane;
      dpp_argmax(v, c);
      const int rstar = __builtin_amdgcn_readlane(c, 63);
      sum += rdlane_f(v, 63);
      const int cstar = __builtin_amdgcn_readlane(rac, rstar);
      rowAlive &= ~(1ull << rstar);
      colAlive &= ~(1ull << cstar);
      const bool stale = ((rowAlive >> lane) & 1ull) && (rac == cstar);
      if (__ballot(stale)) {
        if (stale) row_max_lds(&sub[lane * 65], colAlive, rmv, rac);
      }
    }
  } else {
    float rm[4]; int ra[4];
#pragma unroll
    for (int i = 0; i < 4; ++i) { rm[i] = -INFINITY; ra[i] = -1; }
#pragma unroll
    for (int i = 0; i < 4; ++i) {
      ull m = (i==0) ? arow0 : (i==1) ? arow1 : (i==2) ? arow2 : arow3;
      while (m) {
        const int l = __builtin_ctzll(m); m &= m - 1;
        float rv; int rc;
        rescan_row(Sp, i*64 + l, acol0, acol1, acol2, acol3, lane, rv, rc);
        if (lane == l) { rm[i] = rv; ra[i] = rc; }
      }
    }

    for (int it = picks; it < NN; ++it) {
      float v = rm[0]; int c = lane;
      if (rm[1] > v) { v = rm[1]; c = 64 + lane; }
      if (rm[2] > v) { v = rm[2]; c = 128 + lane; }
      if (rm[3] > v) { v = rm[3]; c = 192 + lane; }
      dpp_argmax(v, c);
      const int   br  = __builtin_amdgcn_readlane(c, 63);
      const float bvv = rdlane_f(v, 63);
      sum += bvv;

      const int bslot = br >> 6, blane = br & 63;
      int myra = ra[0];
      if (bslot == 1) myra = ra[1];
      if (bslot == 2) myra = ra[2];
      if (bslot == 3) myra = ra[3];
      const int bc = __builtin_amdgcn_readlane(myra, blane);

      if (lane == blane) {
        if (bslot == 0) { rm[0] = -INFINITY; ra[0] = -1; }
        if (bslot == 1) { rm[1] = -INFINITY; ra[1] = -1; }
        if (bslot == 2) { rm[2] = -INFINITY; ra[2] = -1; }
        if (bslot == 3) { rm[3] = -INFINITY; ra[3] = -1; }
      }
      const ull cb = ~(1ull << (bc & 63));
      if      (bc < 64)  acol0 &= cb;
      else if (bc < 128) acol1 &= cb;
      else if (bc < 192) acol2 &= cb;
      else               acol3 &= cb;

#pragma unroll
      for (int i = 0; i < 4; ++i) {
        ull m = __ballot(ra[i] == bc);
        while (m) {
          const int l = __builtin_ctzll(m); m &= m - 1;
          float rv; int rc;
          rescan_row(Sp, i*64 + l, acol0, acol1, acol2, acol3, lane, rv, rc);
          if (lane == l) { rm[i] = rv; ra[i] = rc; }
        }
      }
    }
  }
  return sum;
}

// ------ Kernel 2a: collect + bitonic sort (8 waves), keys -> global --------
__global__ __launch_bounds__(512) void collect_sort(const float* __restrict__ S,
                                                    ull* __restrict__ gkeys,
                                                    int* __restrict__ gcnt) {
  const int pair = blockIdx.x;
  const float* Sp = S + (size_t)pair * NN * NN;
  const int tid  = threadIdx.x;
  const int lane = tid & 63;
  const int wv   = tid >> 6;

  __shared__ ull keys[CAPS];           // 16 KB
  __shared__ int lcount;
  if (tid == 0) lcount = 0;
  __syncthreads();

  // ---- collect entries > THRESH ----
  const float4* S4 = (const float4*)Sp;
#pragma unroll 4
  for (int i4 = tid; i4 < NN*NN/4; i4 += 512) {
    float4 x = S4[i4];
    float xv[4] = {x.x, x.y, x.z, x.w};
#pragma unroll
    for (int e = 0; e < 4; ++e) {
      if (xv[e] > THRESH) {
        unsigned b = __float_as_uint(xv[e]);
        unsigned u = (b & 0x80000000u) ? ~b : (b | 0x80000000u);  // monotone asc
        int pos = atomicAdd(&lcount, 1);
        if (pos < CAPS)
          keys[pos] = ((ull)(~u) << 32) | (unsigned)(i4*4 + e);
      }
    }
  }
  __syncthreads();
  int count = lcount;
  if (count > CAPS) count = 0;         // overflow => exact fallback downstream
  for (int i = count + tid; i < CAPS; i += 512) keys[i] = ~0ull;
  __syncthreads();

  // ---- bitonic sort ascending; wave-local 256-elem chunks ----
#define CMPSWAP(I, K)                                                          \
  {                                                                            \
    unsigned ixj = (I) ^ j;                                                    \
    if (ixj > (I)) {                                                           \
      ull a = keys[(I)], b = keys[ixj];                                        \
      bool asc = (((I) & (K)) == 0);                                           \
      if ((a > b) == asc) { keys[(I)] = b; keys[ixj] = a; }                    \
    }                                                                          \
  }

  const unsigned wbase = wv * 256;
  for (unsigned k = 2; k <= 256; k <<= 1)
    for (unsigned j = k >> 1; j > 0; j >>= 1) {
      for (unsigned t = lane; t < 256; t += 64) { unsigned i = wbase + t; CMPSWAP(i, k) }
      __builtin_amdgcn_wave_barrier();
    }
  __syncthreads();
  // k=512: j=256 cross, then local
  { unsigned j = 256; for (unsigned i = tid; i < CAPS; i += 512) CMPSWAP(i, 512) }
  __syncthreads();
  for (unsigned j = 128; j > 0; j >>= 1) {
    for (unsigned t = lane; t < 256; t += 64) { unsigned i = wbase + t; CMPSWAP(i, 512) }
    __builtin_amdgcn_wave_barrier();
  }
  __syncthreads();
  // k=1024: j=512,256 cross, then local
  { unsigned j = 512; for (unsigned i = tid; i < CAPS; i += 512) CMPSWAP(i, 1024) }
  __syncthreads();
  { unsigned j = 256; for (unsigned i = tid; i < CAPS; i += 512) CMPSWAP(i, 1024) }
  __syncthreads();
  for (unsigned j = 128; j > 0; j >>= 1) {
    for (unsigned t = lane; t < 256; t += 64) { unsigned i = wbase + t; CMPSWAP(i, 1024) }
    __builtin_amdgcn_wave_barrier();
  }
  __syncthreads();
  // k=2048: j=1024,512,256 cross, then local
  { unsigned j = 1024; for (unsigned i = tid; i < CAPS; i += 512) CMPSWAP(i, 2048) }
  __syncthreads();
  { unsigned j = 512; for (unsigned i = tid; i < CAPS; i += 512) CMPSWAP(i, 2048) }
  __syncthreads();
  { unsigned j = 256; for (unsigned i = tid; i < CAPS; i += 512) CMPSWAP(i, 2048) }
  __syncthreads();
  for (unsigned j = 128; j > 0; j >>= 1) {
    for (unsigned t = lane; t < 256; t += 64) { unsigned i = wbase + t; CMPSWAP(i, 2048) }
    __builtin_amdgcn_wave_barrier();
  }
#undef CMPSWAP
  __syncthreads();

  for (int i = tid; i < count; i += 512) gkeys[(size_t)pair * CAPS + i] = keys[i];
  if (tid == 0) gcnt[pair] = count;
}

// ------ Kernel 2b: ordered scan (phase 3 only), 1 wave per pair ------------
// Kill bookkeeping in per-lane VGPR nibbles (bit i of lane l = row/col i*64+l);
// batch init via ds_bpermute; 256-bit masks reconstructed once at the end.
__global__ __launch_bounds__(64) void scan_match(const ull* __restrict__ gkeys,
                                                 const int* __restrict__ gcnt,
                                                 ull* __restrict__ gmask,
                                                 float* __restrict__ gsum,
                                                 int* __restrict__ gpicks) {
  const int pair = blockIdx.x;
  const int lane = threadIdx.x;
  const int count = gcnt[pair];
  const ull* kp = gkeys + (size_t)pair * CAPS;

  unsigned rowAlive = 0xFu, colAlive = 0xFu;   // 4 rows/cols per lane
  float sum = 0.0f;
  int picks = 0;

  // prefetch first batch
  ull key = ~0ull;
  if (count > 0) { int i0 = (lane < count) ? lane : 0; key = kp[i0]; }

  for (int base = 0; base < count && picks < NN; base += 64) {
    // issue next batch's load before processing current (hides latency)
    ull nkey = ~0ull;
    const int nbase = base + 64;
    if (nbase < count) { int ni = nbase + lane; if (ni >= count) ni = nbase; nkey = kp[ni]; }

    const int flat = (int)(unsigned)key;
    const int r = (flat >> 8) & 255, c = flat & 255;
    const unsigned u = ~(unsigned)(key >> 32);
    const float val = __uint_as_float((u & 0x80000000u) ? (u ^ 0x80000000u) : ~u);
    const bool valid = (base + lane) < count;

    // batch init: fetch alive bits of (r,c) from owning lanes
    const int rbits = __builtin_amdgcn_ds_bpermute((r & 63) << 2, (int)rowAlive);
    const int cbits = __builtin_amdgcn_ds_bpermute((c & 63) << 2, (int)colAlive);
    bool alive = valid && (((rbits >> (r >> 6)) & 1) != 0) && (((cbits >> (c >> 6)) & 1) != 0);

    // per-pick recurrence: ballot -> ctz -> readlane -> compare-kill
    while (true) {
      const ull mb = __ballot(alive);
      if (!mb) break;
      const int t   = __builtin_ctzll(mb);       // lowest lane = sorted order
      const int r_t = __builtin_amdgcn_readlane(r, t);
      const int c_t = __builtin_amdgcn_readlane(c, t);
      sum += rdlane_f(val, t);
      ++picks;
      alive = alive && (r != r_t) && (c != c_t);
      rowAlive &= ~((lane == (r_t & 63) ? 1u : 0u) << (r_t >> 6));
      colAlive &= ~((lane == (c_t & 63) ? 1u : 0u) << (c_t >> 6));
      if (picks == NN) break;
    }
    key = nkey;
  }

  // reconstruct 256-bit masks (8 ballots) and persist state
  ull m[8];
#pragma unroll
  for (int i = 0; i < 4; ++i) m[i]     = __ballot(((rowAlive >> i) & 1u) != 0);
#pragma unroll
  for (int i = 0; i < 4; ++i) m[4 + i] = __ballot(((colAlive >> i) & 1u) != 0);
  if (lane == 0) {
    ull* mp = gmask + (size_t)pair * 8;
#pragma unroll
    for (int i = 0; i < 8; ++i) mp[i] = m[i];
    gsum[pair]   = sum;
    gpicks[pair] = picks;
  }
}

// ------ Kernel 2c: tail greedy on remaining alive submatrix ----------------
__global__ __launch_bounds__(64) void tail_match(const float* __restrict__ S,
                                                 const ull* __restrict__ gmask,
                                                 const float* __restrict__ gsum,
                                                 const int* __restrict__ gpicks,
                                                 float* __restrict__ out) {
  const int pair = blockIdx.x;
  const int lane = threadIdx.x;
  const float* Sp = S + (size_t)pair * NN * NN;

  __shared__ float sub[64 * 65];       // 16.6 KB compacted submatrix

  float sum = gsum[pair];
  int picks = gpicks[pair];

  if (picks < NN) {
    const ull* mp = gmask + (size_t)pair * 8;
    ull arow0 = mp[0], arow1 = mp[1], arow2 = mp[2], arow3 = mp[3];
    ull acol0 = mp[4], acol1 = mp[5], acol2 = mp[6], acol3 = mp[7];
    int k = NN - picks;

    if (k > 64) {
      // rare path: per-lane own-row maxes; single picks until k == 64
      float rm[4]; int ra[4];
#pragma unroll
      for (int i = 0; i < 4; ++i) { rm[i] = -INFINITY; ra[i] = -1; }
      {
        const bool a0 = ((arow0 >> lane) & 1ull) != 0;
        if (a0) scan_own_row(Sp + (size_t)lane * NN, acol0, acol1, acol2, acol3, rm[0], ra[0]);
        const bool a1 = ((arow1 >> lane) & 1ull) != 0;
        if (a1) scan_own_row(Sp + (size_t)(64 + lane) * NN, acol0, acol1, acol2, acol3, rm[1], ra[1]);
        const bool a2 = ((arow2 >> lane) & 1ull) != 0;
        if (a2) scan_own_row(Sp + (size_t)(128 + lane) * NN, acol0, acol1, acol2, acol3, rm[2], ra[2]);
        const bool a3 = ((arow3 >> lane) & 1ull) != 0;
        if (a3) scan_own_row(Sp + (size_t)(192 + lane) * NN, acol0, acol1, acol2, acol3, rm[3], ra[3]);
      }
      while (k > 64) {
        float v = rm[0]; int c = lane;             // c == original row index
        if (rm[1] > v) { v = rm[1]; c = 64 + lane; }
        if (rm[2] > v) { v = rm[2]; c = 128 + lane; }
        if (rm[3] > v) { v = rm[3]; c = 192 + lane; }
        dpp_argmax(v, c);
        const int br = __builtin_amdgcn_readlane(c, 63);
        sum += rdlane_f(v, 63);
        ++picks; --k;

        const int bslot = br >> 6, blane = br & 63;
        int myra = ra[0];
        if (bslot == 1) myra = ra[1];
        if (bslot == 2) myra = ra[2];
        if (bslot == 3) myra = ra[3];
        const int bc = __builtin_amdgcn_readlane(myra, blane);

        if (lane == blane) {
          if (bslot == 0) { rm[0] = -INFINITY; ra[0] = -1; }
          if (bslot == 1) { rm[1] = -INFINITY; ra[1] = -1; }
          if (bslot == 2) { rm[2] = -INFINITY; ra[2] = -1; }
          if (bslot == 3) { rm[3] = -INFINITY; ra[3] = -1; }
        }
        { const ull rb = ~(1ull << blane);
          if      (bslot == 0) arow0 &= rb;
          else if (bslot == 1) arow1 &= rb;
          else if (bslot == 2) arow2 &= rb;
          else                 arow3 &= rb; }
        { const ull cb = ~(1ull << (bc & 63));
          if      (bc < 64)  acol0 &= cb;
          else if (bc < 128) acol1 &= cb;
          else if (bc < 192) acol2 &= cb;
          else               acol3 &= cb; }

        // stale rows rescan their OWN row concurrently (exec-masked)
#pragma unroll
        for (int i = 0; i < 4; ++i) {
          const bool st = (ra[i] == bc);
          if (__ballot(st)) {
            if (st) {
              float nv; int nc;
              scan_own_row(Sp + (size_t)(i*64 + lane) * NN, acol0, acol1, acol2, acol3, nv, nc);
              rm[i] = nv; ra[i] = nc;
            }
          }
        }
      }
    }

    // fast path: compact k x k (k <= 64) into LDS, finish in-wave.
    {
      k = NN - picks;
      const int myRow = nth_set4(arow0, arow1, arow2, arow3, lane);  // lane -> alive row
      const int myCol = nth_set4(acol0, acol1, acol2, acol3, lane);  // lane -> alive col
      const float* rowBase = Sp + (size_t)myRow * NN;
      // fixed-trip fully-unrolled gather: all 64 loads pipeline (counted vmcnt)
#pragma unroll
      for (int j = 0; j < 64; ++j) {
        const int cj = __builtin_amdgcn_readlane(myCol, j);
        sub[lane * 65 + j] = rowBase[cj];
      }
      asm volatile("s_waitcnt lgkmcnt(0)" ::: "memory");
      __builtin_amdgcn_wave_barrier();

      const ull fullMask = (k == 64) ? ~0ull : ((1ull << k) - 1ull);
      ull rAlive = fullMask, cAlive = fullMask;
      float rmv; int rac;
      row_max_lds(&sub[lane * 65], cAlive, rmv, rac);  // garbage rows masked below

      for (int it = 0; it < k; ++it) {
        float v = ((rAlive >> lane) & 1ull) ? rmv : -INFINITY;
        int c = lane;
        dpp_argmax(v, c);            // tie-break lowest lane = lowest orig row
        const int rstar = __builtin_amdgcn_readlane(c, 63);
        sum += rdlane_f(v, 63);
        const int cstar = __builtin_amdgcn_readlane(rac, rstar);
        rAlive &= ~(1ull << rstar);
        cAlive &= ~(1ull << cstar);
        const bool stale = ((rAlive >> lane) & 1ull) && (rac == cstar);
        if (__ballot(stale)) {
          if (stale) row_max_lds(&sub[lane * 65], cAlive, rmv, rac);
        }
      }
    }
  }

  if (lane == 0) out[pair] = tanhf(sum / (float)NN);
}

// ------ Fused fallback (used only if workspace can't fit the keys) ---------
__global__ __launch_bounds__(256) void sort_scan_match(const float* __restrict__ S,
                                                       float* __restrict__ out) {
  const int pair = blockIdx.x;
  const float* Sp = S + (size_t)pair * NN * NN;
  const int tid  = threadIdx.x;
  const int lane = tid & 63;
  const int wv   = tid >> 6;

  __shared__ ull keys[CAPS];
  __shared__ float sub[64 * 65];
  __shared__ int lcount;

  if (tid == 0) lcount = 0;
  __syncthreads();

  const float4* S4 = (const float4*)Sp;
#pragma unroll 4
  for (int i4 = tid; i4 < NN*NN/4; i4 += 256) {
    float4 x = S4[i4];
    float xv[4] = {x.x, x.y, x.z, x.w};
#pragma unroll
    for (int e = 0; e < 4; ++e) {
      if (xv[e] > THRESH) {
        unsigned b = __float_as_uint(xv[e]);
        unsigned u = (b & 0x80000000u) ? ~b : (b | 0x80000000u);
        int pos = atomicAdd(&lcount, 1);
        if (pos < CAPS)
          keys[pos] = ((ull)(~u) << 32) | (unsigned)(i4*4 + e);
      }
    }
  }
  __syncthreads();
  int count = lcount;
  if (count > CAPS) count = 0;
  for (int i = count + tid; i < CAPS; i += 256) keys[i] = ~0ull;
  __syncthreads();

#define CMPSWAP(I, K)                                                          \
  {                                                                            \
    unsigned ixj = (I) ^ j;                                                    \
    if (ixj > (I)) {                                                           \
      ull a = keys[(I)], b = keys[ixj];                                        \
      bool asc = (((I) & (K)) == 0);                                           \
      if ((a > b) == asc) { keys[(I)] = b; keys[ixj] = a; }                    \
    }                                                                          \
  }
  const unsigned wbase = wv * 512;
  for (unsigned k = 2; k <= 512; k <<= 1)
    for (unsigned j = k >> 1; j > 0; j >>= 1) {
      for (unsigned t = lane; t < 512; t += 64) { unsigned i = wbase + t; CMPSWAP(i, k) }
      __builtin_amdgcn_wave_barrier();
    }
  __syncthreads();
  { unsigned j = 512; for (unsigned i = tid; i < CAPS; i += 256) CMPSWAP(i, 1024) }
  __syncthreads();
  for (unsigned j = 256; j > 0; j >>= 1) {
    for (unsigned t = lane; t < 512; t += 64) { unsigned i = wbase + t; CMPSWAP(i, 1024) }
    __builtin_amdgcn_wave_barrier();
  }
  __syncthreads();
  { unsigned j = 1024; for (unsigned i = tid; i < CAPS; i += 256) CMPSWAP(i, 2048) }
  __syncthreads();
  { unsigned j = 512; for (unsigned i = tid; i < CAPS; i += 256) CMPSWAP(i, 2048) }
  __syncthreads();
  for (unsigned j = 256; j > 0; j >>= 1) {
    for (unsigned t = lane; t < 512; t += 64) { unsigned i = wbase + t; CMPSWAP(i, 2048) }
    __builtin_amdgcn_wave_barrier();
  }
  __syncthreads();
#undef CMPSWAP

  if (tid >= 64) return;

  ull arow0 = ~0ull, arow1 = ~0ull, arow2 = ~0ull, arow3 = ~0ull;
  ull acol0 = ~0ull, acol1 = ~0ull, acol2 = ~0ull, acol3 = ~0ull;
  float sum = 0.0f;
  int picks = 0;

  for (int base = 0; base < count && picks < NN; base += 64) {
    const ull key = keys[base + lane];
    const int flat = (int)(unsigned)key;
    const int r = (flat >> 8) & 255, c = flat & 255;
    const unsigned u = ~(unsigned)(key >> 32);
    const float val = __uint_as_float((u & 0x80000000u) ? (u ^ 0x80000000u) : ~u);
    const bool valid = (base + lane) < count;

    const ull rs = (r & 128) ? ((r & 64) ? arow3 : arow2) : ((r & 64) ? arow1 : arow0);
    const ull cs = (c & 128) ? ((c & 64) ? acol3 : acol2) : ((c & 64) ? acol1 : acol0);
    bool alive = valid && (((rs >> (r & 63)) & 1ull) != 0) && (((cs >> (c & 63)) & 1ull) != 0);

    while (true) {
      const ull mb = __ballot(alive);
      if (!mb) break;
      const int t   = __builtin_ctzll(mb);
      const int r_t = __builtin_amdgcn_readlane(r, t);
      const int c_t = __builtin_amdgcn_readlane(c, t);
      sum += rdlane_f(val, t);
      ++picks;
      alive = alive && (r != r_t) && (c != c_t);
      {
        const ull rb = 1ull << (r_t & 63); const int rs6 = r_t >> 6;
        arow0 &= ~((rs6 == 0) ? rb : 0ull);
        arow1 &= ~((rs6 == 1) ? rb : 0ull);
        arow2 &= ~((rs6 == 2) ? rb : 0ull);
        arow3 &= ~((rs6 == 3) ? rb : 0ull);
        const ull cb = 1ull << (c_t & 63); const int cs6 = c_t >> 6;
        acol0 &= ~((cs6 == 0) ? cb : 0ull);
        acol1 &= ~((cs6 == 1) ? cb : 0ull);
        acol2 &= ~((cs6 == 2) ? cb : 0ull);
        acol3 &= ~((cs6 == 3) ? cb : 0ull);
      }
      if (picks == NN) break;
    }
  }

  sum = finish_tail(Sp, sub, lane, arow0, arow1, arow2, arow3,
                    acol0, acol1, acol2, acol3, picks, sum);

  if (lane == 0) out[pair] = tanhf(sum / (float)NN);
}

extern "C" void kernel_launch(void* const* d_in, const int* in_sizes, int n_in,
                              void* d_out, int out_size, void* d_ws, size_t ws_size,
                              hipStream_t stream) {
  const float* x1 = (const float*)d_in[0];
  const float* x2 = (const float*)d_in[1];
  float* out = (float*)d_out;
  float* S   = (float*)d_ws;           // B*N*N*4 = 32 MiB

  const int B = in_sizes[0] / (NN * DD);

  ull* gkeys = (ull*)(S + (size_t)B * NN * NN);       // B*CAPS*8 = 2 MiB
  int* gcnt  = (int*)(gkeys + (size_t)B * CAPS);      // B*4
  const int Bev = (B + 1) & ~1;                       // keep 8B alignment
  ull*   gmask  = (ull*)(gcnt + Bev);                 // B*8 ull
  float* gsum   = (float*)(gmask + (size_t)B * 8);    // B*4
  int*   gpicks = (int*)(gsum + B);                   // B*4
  const size_t need = (size_t)((char*)(gpicks + B) - (char*)d_ws);

  dim3 ggrid(NN / 64, NN / 128, B);    // 4 x 2 x 128 = 1024 blocks
  gemm_bt_mfma<<<ggrid, 256, 0, stream>>>(x1, x2, S);

  if (ws_size >= need) {
    collect_sort<<<B, 512, 0, stream>>>(S, gkeys, gcnt);
    scan_match<<<B, 64, 0, stream>>>(gkeys, gcnt, gmask, gsum, gpicks);
    tail_match<<<B, 64, 0, stream>>>(S, gmask, gsum, gpicks, out);
  } else {
    sort_scan_match<<<B, 256, 0, stream>>>(S, out);   // fused fallback
  }
}